// Round 2
// baseline (327.166 us; speedup 1.0000x reference)
//
#include <hip/hip_runtime.h>

#define N_NODES 100000
#define N_EDGES 1600000
#define IN_DIM 256
#define OUT_DIM 128
#define SCAN_B 1024
#define SCAN_NB 98  // ceil(100000/1024)

__device__ inline unsigned short f2bf(float f) {
    union { float f; unsigned int u; } a; a.f = f;
    unsigned int r = a.u + 0x7fffu + ((a.u >> 16) & 1u);
    return (unsigned short)(r >> 16);
}
__device__ inline float bf2f(unsigned short h) {
    union { unsigned int u; float f; } a; a.u = ((unsigned int)h) << 16;
    return a.f;
}

// ---------------- Kernel 0: u = fsW @ wi, v = fsW @ wj ----------------
__global__ void kuv(const float* __restrict__ fsW, const float* __restrict__ fw,
                    float* __restrict__ u, float* __restrict__ v) {
    __shared__ float wi[128], wj[128];
    int t = threadIdx.x;
    if (t < 128) wi[t] = fw[t]; else wj[t - 128] = fw[t];
    __syncthreads();
    const float* rowp = fsW + (size_t)t * OUT_DIM;
    float su = 0.f, sv = 0.f;
    for (int d = 0; d < 128; d += 4) {
        float4 a = *(const float4*)(rowp + d);
        su += a.x * wi[d] + a.y * wi[d + 1] + a.z * wi[d + 2] + a.w * wi[d + 3];
        sv += a.x * wj[d] + a.y * wj[d + 1] + a.z * wj[d + 2] + a.w * wj[d + 3];
    }
    u[t] = su; v[t] = sv;
}

// ------------- Kernel 1: pre_sup(bf16) = x@W ; si = x.u ; sj = x.v -------------
__global__ __launch_bounds__(256) void gemm_node(
        const float* __restrict__ x, const float* __restrict__ W,
        const float* __restrict__ u, const float* __restrict__ v,
        unsigned short* __restrict__ psb, float* __restrict__ si, float* __restrict__ sj) {
    __shared__ float xs[64 * 64];      // 16 KB
    __shared__ float Ws_[64 * 128];    // 32 KB
    __shared__ float us_[64], vs_[64];

    const int t = threadIdx.x;
    const int ng = t >> 5, cg = t & 31;      // node-group (8 nodes), col-group (4 cols)
    const int rrow = t >> 2, quad = t & 3;   // staging / si-epilogue roles
    const int brow = blockIdx.x * 64;

    float acc[8][4];
#pragma unroll
    for (int i = 0; i < 8; ++i)
#pragma unroll
        for (int j = 0; j < 4; ++j) acc[i][j] = 0.f;
    float su = 0.f, sv = 0.f;

    for (int kc = 0; kc < IN_DIM; kc += 64) {
        // ---- stage x tile (64 nodes x 64 k) ----
        {
            int gnode = brow + rrow;
            const float* xrow = x + (size_t)gnode * IN_DIM + kc;
#pragma unroll
            for (int ii = 0; ii < 4; ++ii) {
                int kk = ii * 16 + quad * 4;
                float4 val = make_float4(0.f, 0.f, 0.f, 0.f);
                if (gnode < N_NODES) val = *(const float4*)(xrow + kk);
                *(float4*)&xs[rrow * 64 + kk] = val;
            }
        }
        // ---- stage W tile (64 k x 128 cols, contiguous in global) ----
#pragma unroll
        for (int j = 0; j < 8; ++j) {
            int f = t + j * 256;
            *(float4*)&Ws_[f * 4] = *(const float4*)(W + (size_t)kc * OUT_DIM + f * 4);
        }
        if (t < 16)       *(float4*)&us_[t * 4]        = *(const float4*)&u[kc + t * 4];
        else if (t < 32)  *(float4*)&vs_[(t - 16) * 4] = *(const float4*)&v[kc + (t - 16) * 4];
        __syncthreads();

        // ---- main FMA loop ----
        for (int s = 0; s < 16; ++s) {
            const int k4 = s * 4;
            float4 b0 = *(const float4*)&Ws_[(k4 + 0) * 128 + cg * 4];
            float4 b1 = *(const float4*)&Ws_[(k4 + 1) * 128 + cg * 4];
            float4 b2 = *(const float4*)&Ws_[(k4 + 2) * 128 + cg * 4];
            float4 b3 = *(const float4*)&Ws_[(k4 + 3) * 128 + cg * 4];
#pragma unroll
            for (int i = 0; i < 8; ++i) {
                float4 a = *(const float4*)&xs[(ng * 8 + i) * 64 + k4];
                acc[i][0] = fmaf(a.x, b0.x, acc[i][0]); acc[i][0] = fmaf(a.y, b1.x, acc[i][0]);
                acc[i][0] = fmaf(a.z, b2.x, acc[i][0]); acc[i][0] = fmaf(a.w, b3.x, acc[i][0]);
                acc[i][1] = fmaf(a.x, b0.y, acc[i][1]); acc[i][1] = fmaf(a.y, b1.y, acc[i][1]);
                acc[i][1] = fmaf(a.z, b2.y, acc[i][1]); acc[i][1] = fmaf(a.w, b3.y, acc[i][1]);
                acc[i][2] = fmaf(a.x, b0.z, acc[i][2]); acc[i][2] = fmaf(a.y, b1.z, acc[i][2]);
                acc[i][2] = fmaf(a.z, b2.z, acc[i][2]); acc[i][2] = fmaf(a.w, b3.z, acc[i][2]);
                acc[i][3] = fmaf(a.x, b0.w, acc[i][3]); acc[i][3] = fmaf(a.y, b1.w, acc[i][3]);
                acc[i][3] = fmaf(a.z, b2.w, acc[i][3]); acc[i][3] = fmaf(a.w, b3.w, acc[i][3]);
            }
        }
        // ---- si/sj partial (4 threads per node, 16 k each) ----
        {
            const float* xr = &xs[rrow * 64 + quad * 16];
            const float* ur = &us_[quad * 16];
            const float* vr = &vs_[quad * 16];
#pragma unroll
            for (int m = 0; m < 16; m += 4) {
                float4 a = *(const float4*)(xr + m);
                float4 uu = *(const float4*)(ur + m);
                float4 vv = *(const float4*)(vr + m);
                su = fmaf(a.x, uu.x, su); su = fmaf(a.y, uu.y, su);
                su = fmaf(a.z, uu.z, su); su = fmaf(a.w, uu.w, su);
                sv = fmaf(a.x, vv.x, sv); sv = fmaf(a.y, vv.y, sv);
                sv = fmaf(a.z, vv.z, sv); sv = fmaf(a.w, vv.w, sv);
            }
        }
        __syncthreads();
    }

    // reduce si/sj over the 4 quad lanes (consecutive lanes in-wave)
    su += __shfl_xor(su, 1); su += __shfl_xor(su, 2);
    sv += __shfl_xor(sv, 1); sv += __shfl_xor(sv, 2);
    if (quad == 0) {
        int gn = brow + rrow;
        if (gn < N_NODES) { si[gn] = su; sj[gn] = sv; }
    }

    // write pre_sup as bf16
#pragma unroll
    for (int i = 0; i < 8; ++i) {
        int node = brow + ng * 8 + i;
        if (node < N_NODES) {
            ushort4 o;
            o.x = f2bf(acc[i][0]); o.y = f2bf(acc[i][1]);
            o.z = f2bf(acc[i][2]); o.w = f2bf(acc[i][3]);
            *(ushort4*)&psb[(size_t)node * OUT_DIM + cg * 4] = o;
        }
    }
}

// ---------------- Kernel 2: degree histogram ----------------
__global__ void khist(const int* __restrict__ row, int* __restrict__ deg) {
    int e = blockIdx.x * 256 + threadIdx.x;
    if (e < N_EDGES) atomicAdd(&deg[row[e]], 1);
}

// ---------------- Kernel 3a: per-block exclusive scan ----------------
__global__ void kscan1(const int* __restrict__ deg, int* __restrict__ offs,
                       int* __restrict__ bsum) {
    int i = blockIdx.x * SCAN_B + threadIdx.x;
    int vv = (i < N_NODES) ? deg[i] : 0;
    int lane = threadIdx.x & 63, wid = threadIdx.x >> 6;
    int s = vv;
#pragma unroll
    for (int o = 1; o < 64; o <<= 1) { int tt = __shfl_up(s, o); if (lane >= o) s += tt; }
    __shared__ int wsum[16];
    if (lane == 63) wsum[wid] = s;
    __syncthreads();
    if (threadIdx.x < 16) {
        int tt = wsum[threadIdx.x]; int ss = tt;
#pragma unroll
        for (int o = 1; o < 16; o <<= 1) { int uu = __shfl_up(ss, o); if ((int)threadIdx.x >= o) ss += uu; }
        wsum[threadIdx.x] = ss - tt;  // exclusive prefix of wave sums
    }
    __syncthreads();
    int excl = s - vv + wsum[wid];
    if (i < N_NODES) offs[i] = excl;
    if (threadIdx.x == SCAN_B - 1) bsum[blockIdx.x] = s + wsum[wid];
}

// ---------------- Kernel 3b: scan the 98 block sums ----------------
__global__ void kscan2(const int* __restrict__ bsum, int* __restrict__ boff) {
    int i = threadIdx.x;
    int vv = (i < SCAN_NB) ? bsum[i] : 0;
    int lane = i & 63, wid = i >> 6;
    int s = vv;
#pragma unroll
    for (int o = 1; o < 64; o <<= 1) { int tt = __shfl_up(s, o); if (lane >= o) s += tt; }
    __shared__ int wsum2[2];
    if (lane == 63) wsum2[wid] = s;
    __syncthreads();
    int base = (wid == 1) ? wsum2[0] : 0;
    if (i < SCAN_NB) boff[i] = s - vv + base;
}

// ---------------- Kernel 3c: add block offsets, init cursor ----------------
__global__ void kscan3(int* __restrict__ offs, int* __restrict__ cursor,
                       const int* __restrict__ boff) {
    int i = blockIdx.x * SCAN_B + threadIdx.x;
    if (i < N_NODES) {
        int o = offs[i] + boff[blockIdx.x];
        offs[i] = o;
        cursor[i] = o;
    }
}

// ------- Kernel 4: per-edge score + CSR scatter (col, val) sorted by row -------
__global__ void kscatter(const int* __restrict__ row, const int* __restrict__ col,
                         const float* __restrict__ si, const float* __restrict__ sj,
                         const float* __restrict__ dia, const float* __restrict__ fb,
                         int* __restrict__ cursor, int* __restrict__ ecol,
                         float* __restrict__ eval) {
    int e = blockIdx.x * 256 + threadIdx.x;
    if (e >= N_EDGES) return;
    int r = row[e], c = col[e];
    float tval = si[r] + sj[c] + fb[0];
    float sc = 1.f / (1.f + expf(-tval));
    float l2 = log2f(dia[r] * dia[c]);
    float val = exp2f(-sc * l2);
    int pos = atomicAdd(&cursor[r], 1);
    ecol[pos] = c;
    eval[pos] = val;
}

// ------- Kernel 5: per-node gather-accumulate + ReLU (32 lanes per node) -------
__global__ __launch_bounds__(256) void kgather(
        const int* __restrict__ offs, const int* __restrict__ deg,
        const int* __restrict__ ecol, const float* __restrict__ eval,
        const unsigned short* __restrict__ psb, float* __restrict__ out) {
    int lane = threadIdx.x & 31;
    int node = blockIdx.x * 8 + (threadIdx.x >> 5);
    if (node >= N_NODES) return;
    int start = offs[node], d = deg[node];
    float a0 = 0.f, a1 = 0.f, a2 = 0.f, a3 = 0.f;
    int k = 0;
    for (; k + 2 <= d; k += 2) {
        int c0 = ecol[start + k], c1 = ecol[start + k + 1];
        float v0 = eval[start + k], v1 = eval[start + k + 1];
        ushort4 p0 = *(const ushort4*)&psb[(size_t)c0 * OUT_DIM + lane * 4];
        ushort4 p1 = *(const ushort4*)&psb[(size_t)c1 * OUT_DIM + lane * 4];
        a0 = fmaf(v0, bf2f(p0.x), a0); a0 = fmaf(v1, bf2f(p1.x), a0);
        a1 = fmaf(v0, bf2f(p0.y), a1); a1 = fmaf(v1, bf2f(p1.y), a1);
        a2 = fmaf(v0, bf2f(p0.z), a2); a2 = fmaf(v1, bf2f(p1.z), a2);
        a3 = fmaf(v0, bf2f(p0.w), a3); a3 = fmaf(v1, bf2f(p1.w), a3);
    }
    if (k < d) {
        int c0 = ecol[start + k];
        float v0 = eval[start + k];
        ushort4 p0 = *(const ushort4*)&psb[(size_t)c0 * OUT_DIM + lane * 4];
        a0 = fmaf(v0, bf2f(p0.x), a0);
        a1 = fmaf(v0, bf2f(p0.y), a1);
        a2 = fmaf(v0, bf2f(p0.z), a2);
        a3 = fmaf(v0, bf2f(p0.w), a3);
    }
    float4 o;
    o.x = fmaxf(a0, 0.f); o.y = fmaxf(a1, 0.f);
    o.z = fmaxf(a2, 0.f); o.w = fmaxf(a3, 0.f);
    *(float4*)&out[(size_t)node * OUT_DIM + lane * 4] = o;
}

extern "C" void kernel_launch(void* const* d_in, const int* in_sizes, int n_in,
                              void* d_out, int out_size, void* d_ws, size_t ws_size,
                              hipStream_t stream) {
    const float* x   = (const float*)d_in[0];
    const float* W   = (const float*)d_in[1];
    const float* fsW = (const float*)d_in[2];
    const float* fw  = (const float*)d_in[3];
    const float* fb  = (const float*)d_in[4];
    const float* dia = (const float*)d_in[5];
    const int*   row = (const int*)d_in[6];
    const int*   col = (const int*)d_in[7];
    float* out = (float*)d_out;

    char* p = (char*)d_ws;
    auto alloc = [&](size_t bytes) -> char* {
        char* r = p; p += (bytes + 255) & ~(size_t)255; return r;
    };
    float* u      = (float*)alloc(256 * 4);
    float* v      = (float*)alloc(256 * 4);
    float* si     = (float*)alloc((size_t)N_NODES * 4);
    float* sj     = (float*)alloc((size_t)N_NODES * 4);
    int*   deg    = (int*)alloc((size_t)N_NODES * 4);
    int*   offs   = (int*)alloc((size_t)N_NODES * 4);
    int*   cursor = (int*)alloc((size_t)N_NODES * 4);
    int*   bsum   = (int*)alloc(128 * 4);
    int*   boff   = (int*)alloc(128 * 4);
    unsigned short* psb = (unsigned short*)alloc((size_t)N_NODES * OUT_DIM * 2);
    int*   ecol   = (int*)alloc((size_t)N_EDGES * 4);
    float* eval   = (float*)alloc((size_t)N_EDGES * 4);

    (void)hipMemsetAsync(deg, 0, (size_t)N_NODES * 4, stream);

    kuv<<<1, 256, 0, stream>>>(fsW, fw, u, v);
    gemm_node<<<(N_NODES + 63) / 64, 256, 0, stream>>>(x, W, u, v, psb, si, sj);
    khist<<<N_EDGES / 256, 256, 0, stream>>>(row, deg);
    kscan1<<<SCAN_NB, SCAN_B, 0, stream>>>(deg, offs, bsum);
    kscan2<<<1, 128, 0, stream>>>(bsum, boff);
    kscan3<<<SCAN_NB, SCAN_B, 0, stream>>>(offs, cursor, boff);
    kscatter<<<N_EDGES / 256, 256, 0, stream>>>(row, col, si, sj, dia, fb, cursor, ecol, eval);
    kgather<<<N_NODES / 8, 256, 0, stream>>>(offs, deg, ecol, eval, psb, out);
}

// Round 4
// 291.541 us; speedup vs baseline: 1.1222x; 1.1222x over previous
//
#include <hip/hip_runtime.h>

#define N_NODES 100000
#define N_EDGES 1600000
#define IN_DIM 256
#define OUT_DIM 128
#define SCAN_B 1024
#define SCAN_NB 98  // ceil(100000/1024)

typedef __attribute__((ext_vector_type(4))) float f32x4;
typedef __attribute__((ext_vector_type(8))) short s16x8;

__device__ inline unsigned short f2bf(float f) {
    union { float f; unsigned int u; } a; a.f = f;
    unsigned int r = a.u + 0x7fffu + ((a.u >> 16) & 1u);
    return (unsigned short)(r >> 16);
}
__device__ inline float bf2f(unsigned short h) {
    union { unsigned int u; float f; } a; a.u = ((unsigned int)h) << 16;
    return a.f;
}

// ---------------- Kernel 0: u = fsW @ wi, v = fsW @ wj ----------------
__global__ void kuv(const float* __restrict__ fsW, const float* __restrict__ fw,
                    float* __restrict__ u, float* __restrict__ v) {
    __shared__ float wi[128], wj[128];
    int t = threadIdx.x;
    if (t < 128) wi[t] = fw[t]; else wj[t - 128] = fw[t];
    __syncthreads();
    const float* rowp = fsW + (size_t)t * OUT_DIM;
    float su = 0.f, sv = 0.f;
    for (int d = 0; d < 128; d += 4) {
        float4 a = *(const float4*)(rowp + d);
        su += a.x * wi[d] + a.y * wi[d + 1] + a.z * wi[d + 2] + a.w * wi[d + 3];
        sv += a.x * wj[d] + a.y * wj[d + 1] + a.z * wj[d + 2] + a.w * wj[d + 3];
    }
    u[t] = su; v[t] = sv;
}

// ---------------- Kernel 0b: wt[n][k] = bf16(W[k][n])  (128 x 256) ----------------
__global__ void kwt(const float* __restrict__ W, unsigned short* __restrict__ wt) {
    int n = blockIdx.x;       // 0..127
    int k = threadIdx.x;      // 0..255
    wt[n * 256 + k] = f2bf(W[(size_t)k * 128 + n]);
}

// ------- Kernel 1: pre_sup(bf16) = x@W via MFMA ; si = x.u ; sj = x.v -------
// Block: 256 thr (4 waves). Tile: 64 nodes x 128 cols, K staged in 2 phases of 128.
// Wave w computes cols [w*32, w*32+32). LDS rows padded to 136 ushorts (272 B).
__global__ __launch_bounds__(256) void gemm_mfma(
        const float* __restrict__ x, const unsigned short* __restrict__ wt,
        const float* __restrict__ u, const float* __restrict__ v,
        unsigned short* __restrict__ psb, float* __restrict__ si, float* __restrict__ sj) {
    __shared__ unsigned short xa[64 * 136];    // 17408 B
    __shared__ unsigned short wb[128 * 136];   // 34816 B

    const int t = threadIdx.x;
    const int wave = t >> 6, lane = t & 63;
    const int l15 = lane & 15, lhi = lane >> 4;
    const int row = t >> 2, quad = t & 3;      // staging roles
    const int brow = blockIdx.x * 64;
    const int gnode = brow + row;
    const bool valid = gnode < N_NODES;

    f32x4 acc[4][2];
#pragma unroll
    for (int mi = 0; mi < 4; ++mi)
#pragma unroll
        for (int ni = 0; ni < 2; ++ni) acc[mi][ni] = (f32x4){0.f, 0.f, 0.f, 0.f};
    float su = 0.f, sv = 0.f;

#pragma unroll
    for (int ph = 0; ph < 2; ++ph) {
        // ---- stage x half-tile (64 nodes x 128 k), f32 -> bf16, + si/sj partials ----
        {
            const float* xp = x + (size_t)gnode * IN_DIM + ph * 128 + quad * 32;
            const float* up = u + ph * 128 + quad * 32;
            const float* vp = v + ph * 128 + quad * 32;
#pragma unroll
            for (int cc = 0; cc < 4; ++cc) {
                float4 a0 = make_float4(0.f, 0.f, 0.f, 0.f), a1 = a0;
                if (valid) {
                    a0 = ((const float4*)xp)[cc * 2];
                    a1 = ((const float4*)xp)[cc * 2 + 1];
                    float4 u0 = ((const float4*)up)[cc * 2], u1 = ((const float4*)up)[cc * 2 + 1];
                    float4 v0 = ((const float4*)vp)[cc * 2], v1 = ((const float4*)vp)[cc * 2 + 1];
                    su = fmaf(a0.x, u0.x, su); su = fmaf(a0.y, u0.y, su);
                    su = fmaf(a0.z, u0.z, su); su = fmaf(a0.w, u0.w, su);
                    su = fmaf(a1.x, u1.x, su); su = fmaf(a1.y, u1.y, su);
                    su = fmaf(a1.z, u1.z, su); su = fmaf(a1.w, u1.w, su);
                    sv = fmaf(a0.x, v0.x, sv); sv = fmaf(a0.y, v0.y, sv);
                    sv = fmaf(a0.z, v0.z, sv); sv = fmaf(a0.w, v0.w, sv);
                    sv = fmaf(a1.x, v1.x, sv); sv = fmaf(a1.y, v1.y, sv);
                    sv = fmaf(a1.z, v1.z, sv); sv = fmaf(a1.w, v1.w, sv);
                }
                union { unsigned short h[8]; uint4 q; } pk;
                pk.h[0] = f2bf(a0.x); pk.h[1] = f2bf(a0.y); pk.h[2] = f2bf(a0.z); pk.h[3] = f2bf(a0.w);
                pk.h[4] = f2bf(a1.x); pk.h[5] = f2bf(a1.y); pk.h[6] = f2bf(a1.z); pk.h[7] = f2bf(a1.w);
                *(uint4*)&xa[row * 136 + quad * 32 + cc * 8] = pk.q;
            }
        }
        // ---- stage wt half-tile (128 n-rows x 128 k), bf16 copy ----
        {
            const int wrow = t >> 1, half = t & 1;
            const unsigned short* wp = wt + (size_t)wrow * 256 + ph * 128 + half * 64;
#pragma unroll
            for (int c = 0; c < 8; ++c)
                *(uint4*)&wb[wrow * 136 + half * 64 + c * 8] = ((const uint4*)wp)[c];
        }
        __syncthreads();

        // ---- 4 K-steps of MFMA ----
#pragma unroll
        for (int ks = 0; ks < 4; ++ks) {
            const int k0 = ks * 32 + lhi * 8;
            s16x8 afr[4], bfr[2];
#pragma unroll
            for (int mi = 0; mi < 4; ++mi)
                afr[mi] = *(const s16x8*)&xa[(mi * 16 + l15) * 136 + k0];
#pragma unroll
            for (int ni = 0; ni < 2; ++ni)
                bfr[ni] = *(const s16x8*)&wb[(wave * 32 + ni * 16 + l15) * 136 + k0];
#pragma unroll
            for (int mi = 0; mi < 4; ++mi)
#pragma unroll
                for (int ni = 0; ni < 2; ++ni)
                    acc[mi][ni] = __builtin_amdgcn_mfma_f32_16x16x32_bf16(
                        afr[mi], bfr[ni], acc[mi][ni], 0, 0, 0);
        }
        __syncthreads();
    }

    // si/sj reduce over quad lanes (consecutive lanes)
    su += __shfl_xor(su, 1); su += __shfl_xor(su, 2);
    sv += __shfl_xor(sv, 1); sv += __shfl_xor(sv, 2);
    if (quad == 0 && valid) { si[gnode] = su; sj[gnode] = sv; }

    // C write: D frag mapping col=lane&15, row=(lane>>4)*4+j
#pragma unroll
    for (int mi = 0; mi < 4; ++mi) {
        int node = brow + mi * 16 + lhi * 4;
        if (node + 3 < N_NODES || node < N_NODES) {
#pragma unroll
            for (int ni = 0; ni < 2; ++ni) {
                int colb = wave * 32 + ni * 16 + l15;
#pragma unroll
                for (int j = 0; j < 4; ++j) {
                    if (node + j < N_NODES)
                        psb[(size_t)(node + j) * OUT_DIM + colb] = f2bf(acc[mi][ni][j]);
                }
            }
        }
    }
}

// ---------------- Kernel 2: degree histogram ----------------
__global__ void khist(const int* __restrict__ row, int* __restrict__ deg) {
    int e = blockIdx.x * 256 + threadIdx.x;
    if (e < N_EDGES) atomicAdd(&deg[row[e]], 1);
}

// ---------------- Kernel 3a: per-block exclusive scan ----------------
__global__ void kscan1(const int* __restrict__ deg, int* __restrict__ offs,
                       int* __restrict__ bsum) {
    int i = blockIdx.x * SCAN_B + threadIdx.x;
    int vv = (i < N_NODES) ? deg[i] : 0;
    int lane = threadIdx.x & 63, wid = threadIdx.x >> 6;
    int s = vv;
#pragma unroll
    for (int o = 1; o < 64; o <<= 1) { int tt = __shfl_up(s, o); if (lane >= o) s += tt; }
    __shared__ int wsum[16];
    if (lane == 63) wsum[wid] = s;
    __syncthreads();
    if (threadIdx.x < 16) {
        int tt = wsum[threadIdx.x]; int ss = tt;
#pragma unroll
        for (int o = 1; o < 16; o <<= 1) { int uu = __shfl_up(ss, o); if ((int)threadIdx.x >= o) ss += uu; }
        wsum[threadIdx.x] = ss - tt;  // exclusive prefix of wave sums
    }
    __syncthreads();
    int excl = s - vv + wsum[wid];
    if (i < N_NODES) offs[i] = excl;
    if (threadIdx.x == SCAN_B - 1) bsum[blockIdx.x] = s + wsum[wid];
}

// ---------------- Kernel 3b: scan the 98 block sums ----------------
__global__ void kscan2(const int* __restrict__ bsum, int* __restrict__ boff) {
    int i = threadIdx.x;
    int vv = (i < SCAN_NB) ? bsum[i] : 0;
    int lane = i & 63, wid = i >> 6;
    int s = vv;
#pragma unroll
    for (int o = 1; o < 64; o <<= 1) { int tt = __shfl_up(s, o); if (lane >= o) s += tt; }
    __shared__ int wsum2[2];
    if (lane == 63) wsum2[wid] = s;
    __syncthreads();
    int base = (wid == 1) ? wsum2[0] : 0;
    if (i < SCAN_NB) boff[i] = s - vv + base;
}

// ---------------- Kernel 3c: add block offsets, init cursor ----------------
__global__ void kscan3(int* __restrict__ offs, int* __restrict__ cursor,
                       const int* __restrict__ boff) {
    int i = blockIdx.x * SCAN_B + threadIdx.x;
    if (i < N_NODES) {
        int o = offs[i] + boff[blockIdx.x];
        offs[i] = o;
        cursor[i] = o;
    }
}

// ------- Kernel 4: per-edge score + CSR scatter (packed int2) sorted by row -------
__global__ void kscatter(const int* __restrict__ row, const int* __restrict__ col,
                         const float* __restrict__ si, const float* __restrict__ sj,
                         const float* __restrict__ dia, const float* __restrict__ fb,
                         int* __restrict__ cursor, int2* __restrict__ epack) {
    int e = blockIdx.x * 256 + threadIdx.x;
    if (e >= N_EDGES) return;
    int r = row[e], c = col[e];
    float tval = si[r] + sj[c] + fb[0];
    float sc = 1.f / (1.f + expf(-tval));
    float l2 = log2f(dia[r] * dia[c]);
    float val = exp2f(-sc * l2);
    int pos = atomicAdd(&cursor[r], 1);
    epack[pos] = make_int2(c, __float_as_int(val));
}

// ------- Kernel 5: per-node gather-accumulate + ReLU (32 lanes per node) -------
__global__ __launch_bounds__(256) void kgather(
        const int* __restrict__ offs, const int* __restrict__ deg,
        const int2* __restrict__ epack,
        const unsigned short* __restrict__ psb, float* __restrict__ out) {
    int lane = threadIdx.x & 31;
    int node = blockIdx.x * 8 + (threadIdx.x >> 5);
    if (node >= N_NODES) return;
    int start = offs[node], d = deg[node];
    const int2* ep = epack + start;
    float a0 = 0.f, a1 = 0.f, a2 = 0.f, a3 = 0.f;
    int k = 0;
    for (; k + 2 <= d; k += 2) {
        int2 e0 = ep[k], e1 = ep[k + 1];
        float v0 = __int_as_float(e0.y), v1 = __int_as_float(e1.y);
        ushort4 p0 = *(const ushort4*)&psb[(size_t)e0.x * OUT_DIM + lane * 4];
        ushort4 p1 = *(const ushort4*)&psb[(size_t)e1.x * OUT_DIM + lane * 4];
        a0 = fmaf(v0, bf2f(p0.x), a0); a0 = fmaf(v1, bf2f(p1.x), a0);
        a1 = fmaf(v0, bf2f(p0.y), a1); a1 = fmaf(v1, bf2f(p1.y), a1);
        a2 = fmaf(v0, bf2f(p0.z), a2); a2 = fmaf(v1, bf2f(p1.z), a2);
        a3 = fmaf(v0, bf2f(p0.w), a3); a3 = fmaf(v1, bf2f(p1.w), a3);
    }
    if (k < d) {
        int2 e0 = ep[k];
        float v0 = __int_as_float(e0.y);
        ushort4 p0 = *(const ushort4*)&psb[(size_t)e0.x * OUT_DIM + lane * 4];
        a0 = fmaf(v0, bf2f(p0.x), a0);
        a1 = fmaf(v0, bf2f(p0.y), a1);
        a2 = fmaf(v0, bf2f(p0.z), a2);
        a3 = fmaf(v0, bf2f(p0.w), a3);
    }
    float4 o;
    o.x = fmaxf(a0, 0.f); o.y = fmaxf(a1, 0.f);
    o.z = fmaxf(a2, 0.f); o.w = fmaxf(a3, 0.f);
    *(float4*)&out[(size_t)node * OUT_DIM + lane * 4] = o;
}

extern "C" void kernel_launch(void* const* d_in, const int* in_sizes, int n_in,
                              void* d_out, int out_size, void* d_ws, size_t ws_size,
                              hipStream_t stream) {
    const float* x   = (const float*)d_in[0];
    const float* W   = (const float*)d_in[1];
    const float* fsW = (const float*)d_in[2];
    const float* fw  = (const float*)d_in[3];
    const float* fb  = (const float*)d_in[4];
    const float* dia = (const float*)d_in[5];
    const int*   row = (const int*)d_in[6];
    const int*   col = (const int*)d_in[7];
    float* out = (float*)d_out;

    char* p = (char*)d_ws;
    auto alloc = [&](size_t bytes) -> char* {
        char* r = p; p += (bytes + 255) & ~(size_t)255; return r;
    };
    float* u      = (float*)alloc(256 * 4);
    float* v      = (float*)alloc(256 * 4);
    unsigned short* wtb = (unsigned short*)alloc((size_t)128 * 256 * 2);
    float* si     = (float*)alloc((size_t)N_NODES * 4);
    float* sj     = (float*)alloc((size_t)N_NODES * 4);
    int*   deg    = (int*)alloc((size_t)N_NODES * 4);
    int*   offs   = (int*)alloc((size_t)N_NODES * 4);
    int*   cursor = (int*)alloc((size_t)N_NODES * 4);
    int*   bsum   = (int*)alloc(128 * 4);
    int*   boff   = (int*)alloc(128 * 4);
    unsigned short* psb = (unsigned short*)alloc((size_t)N_NODES * OUT_DIM * 2);
    int2*  epack  = (int2*)alloc((size_t)N_EDGES * 8);

    (void)hipMemsetAsync(deg, 0, (size_t)N_NODES * 4, stream);

    kuv<<<1, 256, 0, stream>>>(fsW, fw, u, v);
    kwt<<<128, 256, 0, stream>>>(W, wtb);
    gemm_mfma<<<(N_NODES + 63) / 64, 256, 0, stream>>>(x, wtb, u, v, psb, si, sj);
    khist<<<N_EDGES / 256, 256, 0, stream>>>(row, deg);
    kscan1<<<SCAN_NB, SCAN_B, 0, stream>>>(deg, offs, bsum);
    kscan2<<<1, 128, 0, stream>>>(bsum, boff);
    kscan3<<<SCAN_NB, SCAN_B, 0, stream>>>(offs, cursor, boff);
    kscatter<<<N_EDGES / 256, 256, 0, stream>>>(row, col, si, sj, dia, fb, cursor, epack);
    kgather<<<N_NODES / 8, 256, 0, stream>>>(offs, deg, epack, psb, out);
}